// Round 17
// baseline (515.953 us; speedup 1.0000x reference)
//
#include <hip/hip_runtime.h>
#include <hip/hip_bf16.h>
#include <hip/hip_fp16.h>

#define N_NODES 100000
#define N_EDGES 800000
#define N_GRAPHS 512
#define D 128
#define EPSV 1e-5f

// radix-bucket CSR build params (256-node buckets)
#define NBLK 256
#define EPB  3125
#define NBUK 391          // ceil(100000/256)
#define MAXB 3072

// MFMA GEMM LDS layout (dwords): Ah 64 rows x 68dw, Wt2 128 cols x 68dw
#define LSTR 68
#define WOFF 4352

#define NSLOT 256         // stats scatter slots (queue depth 25000/256 ~ 98)

typedef _Float16 half8 __attribute__((ext_vector_type(8)));
typedef float floatx16 __attribute__((ext_vector_type(16)));

__device__ __forceinline__ float relu_f(float x){ return fmaxf(x, 0.0f); }

// inclusive scan of sd[0..511] with 256 threads
__device__ __forceinline__ void scan512(int* sd, int t)
{
    for (int off = 1; off < 512; off <<= 1){
        int i2 = t + 256;
        int v1 = (t  >= off) ? sd[t  - off] : 0;
        int v2 = (i2 >= off) ? sd[i2 - off] : 0;
        __syncthreads();
        sd[t]  += v1;
        sd[i2] += v2;
        __syncthreads();
    }
}

// redundant per-block BN finalize: reduce NSLOT slot-partials (L2-hot) -> LDS
// scsh[0..127]=scale, scsh[128..255]=shift. Order matches old k_fin2 bit-exactly.
__device__ __forceinline__ void fin_to_lds(const float* __restrict__ Sp,
                                           const float* __restrict__ Qp,
                                           const float* __restrict__ gamma,
                                           const float* __restrict__ beta,
                                           float* scsh, int tid)
{
    int f = tid & 127;
    const float* srcp = (tid < 128) ? Sp : Qp;
    float acc = 0.f;
    #pragma unroll 4
    for (int s2 = 0; s2 < NSLOT; s2++)
        acc += srcp[s2 * 128 + f];
    scsh[tid] = acc;
    __syncthreads();
    if (tid < 128){
        float Sv = scsh[tid];
        float Qv = scsh[tid + 128];
        float mean = Sv * (1.0f / N_NODES);
        float var  = fmaxf(Qv * (1.0f / N_NODES) - mean * mean, 0.0f);
        float inv  = rsqrtf(var + EPSV);
        float gm = gamma[f] * inv;
        scsh[f]       = gm;                    // per-thread owned slots: no race
        scsh[f + 128] = beta[f] - mean * gm;
    }
    __syncthreads();
}

// ---------------- FRONT: p1 histogram (blocks 0..255) | wprep+zero+cnt (256..351)
__global__ __launch_bounds__(256) void k_front(const int* __restrict__ dst,
                                               int* __restrict__ blockHist,
                                               const float* __restrict__ Ws,
                                               unsigned int* __restrict__ wpack,
                                               unsigned int* __restrict__ zbase,
                                               int zn,
                                               const int* __restrict__ batch,
                                               float* __restrict__ cnt,
                                               int* __restrict__ row_ptr)
{
    __shared__ int h[NBUK];
    int j = blockIdx.x, t = threadIdx.x;
    if (j < NBLK){
        for (int u = t; u < NBUK; u += 256) h[u] = 0;
        __syncthreads();
        int e0 = j * EPB;
        for (int e = e0 + t; e < e0 + EPB; e += 256)
            atomicAdd(&h[dst[e] >> 8], 1);
        __syncthreads();
        for (int u = t; u < NBUK; u += 256) blockHist[j * NBUK + u] = h[u];
    } else {
        int b = j - NBLK;                 // 0..95
        int idx = b * 256 + t;
        if (idx == 0) row_ptr[N_NODES] = N_EDGES;
        if (idx < 3 * 128 * 64){
            int l  = idx >> 13;
            int r  = idx & 8191;
            int c  = r >> 6;
            int k2 = r & 63;
            const float* W = Ws + l * D * D;
            __half2 hh = __floats2half2_rn(W[(size_t)(2 * k2) * D + c],
                                           W[(size_t)(2 * k2 + 1) * D + c]);
            wpack[idx] = *(unsigned int*)&hh;
        }
        int stride = 96 * 256;
        for (int i = idx; i < zn; i += stride) zbase[i] = 0u;
        if (idx < N_GRAPHS){
            int g = idx;
            int lo = 0, hi = N_NODES;
            while (lo < hi){ int m = (lo + hi) >> 1; if (batch[m] < g) lo = m + 1; else hi = m; }
            int lb = lo;
            lo = 0; hi = N_NODES;
            while (lo < hi){ int m = (lo + hi) >> 1; if (batch[m] < g + 1) lo = m + 1; else hi = m; }
            cnt[g] = (float)(lo - lb);
        }
    }
}

// ---------------- P2a: per-bucket column scan (NBUK blocks, parallel) ----------
__global__ __launch_bounds__(256) void k_p2a(const int* __restrict__ blockHist,
                                             int* __restrict__ colScan,
                                             int* __restrict__ bucketTotal)
{
    __shared__ int sd[256];
    int b = blockIdx.x, t = threadIdx.x;
    int v = blockHist[t * NBUK + b];
    sd[t] = v;
    __syncthreads();
    for (int off = 1; off < 256; off <<= 1){
        int u = (t >= off) ? sd[t - off] : 0;
        __syncthreads();
        sd[t] += u;
        __syncthreads();
    }
    colScan[t * NBUK + b] = sd[t] - v;
    if (t == 255) bucketTotal[b] = sd[255];
}

// ---------------- P3: scatter edges into bucket-sorted ebuf (LDS cursors) ------
__global__ __launch_bounds__(256) void k_p3(const int* __restrict__ src,
                                            const int* __restrict__ dst,
                                            const int* __restrict__ colScan,
                                            const int* __restrict__ bucketTotal,
                                            int2* __restrict__ ebuf)
{
    __shared__ int sd[512];
    __shared__ int cur[NBUK];
    int j = blockIdx.x, t = threadIdx.x;
    int i2 = t + 256;
    sd[t]  = (t  < NBUK) ? bucketTotal[t]  : 0;
    sd[i2] = (i2 < NBUK) ? bucketTotal[i2] : 0;
    __syncthreads();
    scan512(sd, t);
    if (t < NBUK)
        cur[t]  = (sd[t]  - bucketTotal[t])  + colScan[j * NBUK + t];
    if (i2 < NBUK)
        cur[i2] = (sd[i2] - bucketTotal[i2]) + colScan[j * NBUK + i2];
    __syncthreads();
    int e0 = j * EPB;
    for (int e = e0 + t; e < e0 + EPB; e += 256){
        int s = src[e], d = dst[e];
        int pos = atomicAdd(&cur[d >> 8], 1);
        int2 v; v.x = s; v.y = d;
        ebuf[pos] = v;
    }
}

// ---------------- P4: per-bucket counting sort -> row_ptr, csr_src, dinv, selfw
__global__ __launch_bounds__(256) void k_p4(const int2* __restrict__ ebuf,
                                            const int* __restrict__ bucketTotal,
                                            int* __restrict__ row_ptr,
                                            int* __restrict__ csr_src,
                                            float* __restrict__ dinv,
                                            float* __restrict__ selfw)
{
    __shared__ int2 stash[MAXB];
    __shared__ int sdScan[512];
    __shared__ int bins[256];
    __shared__ int sd[256];
    int b = blockIdx.x, t = threadIdx.x;
    int i2 = t + 256;
    sdScan[t]  = (t  < NBUK) ? bucketTotal[t]  : 0;
    sdScan[i2] = (i2 < NBUK) ? bucketTotal[i2] : 0;
    __syncthreads();
    scan512(sdScan, t);
    int cntb = bucketTotal[b];
    int base = sdScan[b] - cntb;
    bool st = (cntb <= MAXB);
    bins[t] = 0;
    __syncthreads();
    for (int i = t; i < cntb; i += 256){
        int2 ed = ebuf[base + i];
        if (st) stash[i] = ed;
        atomicAdd(&bins[ed.y & 255], 1);
    }
    __syncthreads();
    int a0 = bins[t];
    sd[t] = a0;
    __syncthreads();
    for (int off = 1; off < 256; off <<= 1){
        int v = (t >= off) ? sd[t - off] : 0;
        __syncthreads();
        sd[t] += v;
        __syncthreads();
    }
    int pex = sd[t] - a0;
    int node = b * 256 + t;
    if (node < N_NODES){
        row_ptr[node] = base + pex;
        float d = (float)(a0 + 1);
        dinv[node]  = rsqrtf(d);
        selfw[node] = 1.0f / d;
    }
    __syncthreads();
    bins[t] = pex;
    __syncthreads();
    for (int i = t; i < cntb; i += 256){
        int2 ed = st ? stash[i] : ebuf[base + i];
        int pos = atomicAdd(&bins[ed.y & 255], 1);
        csr_src[base + pos] = ed.x;
    }
}

// ---------------- MFMA GEMM v2 + fused per-block BN finalize -------------------
__global__ __launch_bounds__(256) void k_gemm(const float* __restrict__ A,
                                              const unsigned int* __restrict__ wp,
                                              const float* __restrict__ Sp,
                                              const float* __restrict__ Qp,
                                              const float* __restrict__ gamma,
                                              const float* __restrict__ beta,
                                              __half* __restrict__ outh,
                                              int useBn)
{
    __shared__ unsigned int lds32[WOFF + 128 * LSTR];   // 52224 B
    __shared__ float scsh[256];                          // sc | sh
    int tid = threadIdx.x;
    int rowBase = blockIdx.x * 64;

    if (useBn)
        fin_to_lds(Sp, Qp, gamma, beta, scsh, tid);

    #pragma unroll
    for (int rep = 0; rep < 8; rep++){
        int f  = rep * 256 + tid;
        int m  = f >> 5;
        int c4 = f & 31;
        int row = rowBase + m;
        if (row >= N_NODES) row = N_NODES - 1;
        float4 v = *(const float4*)(A + (size_t)row * D + c4 * 4);
        if (useBn){
            float4 sc = *(const float4*)&scsh[c4 * 4];
            float4 sh = *(const float4*)&scsh[128 + c4 * 4];
            v.x = relu_f(fmaf(v.x, sc.x, sh.x));
            v.y = relu_f(fmaf(v.y, sc.y, sh.y));
            v.z = relu_f(fmaf(v.z, sc.z, sh.z));
            v.w = relu_f(fmaf(v.w, sc.w, sh.w));
        }
        __half2 h0 = __floats2half2_rn(v.x, v.y);
        __half2 h1 = __floats2half2_rn(v.z, v.w);
        uint2 u; u.x = *(unsigned int*)&h0; u.y = *(unsigned int*)&h1;
        *(uint2*)&lds32[m * LSTR + 2 * c4] = u;
    }
    {
        const uint4* gw = (const uint4*)wp;
        #pragma unroll
        for (int rep = 0; rep < 8; rep++){
            int f = rep * 256 + tid;
            int c = f >> 4;
            int q = f & 15;
            uint4 v = gw[f];
            *(uint4*)&lds32[WOFF + c * LSTR + 4 * q] = v;
        }
    }
    __syncthreads();

    int lane = tid & 63, wv = tid >> 6;
    int quad = lane >> 5;
    int ml   = (lane & 31) + (wv & 1) * 32;
    int cA   = (wv >> 1) * 64;
    int c0   = cA + (lane & 31);
    int c1   = c0 + 32;
    const unsigned int* aRow  = lds32 + ml * LSTR;
    const unsigned int* bRow0 = lds32 + WOFF + c0 * LSTR;
    const unsigned int* bRow1 = lds32 + WOFF + c1 * LSTR;
    floatx16 acc0 = {};
    floatx16 acc1 = {};
    #pragma unroll
    for (int ch = 0; ch < 8; ch++){
        int o = ch * 8 + quad * 4;
        half8 af = *(const half8*)(aRow  + o);
        half8 b0 = *(const half8*)(bRow0 + o);
        half8 b1 = *(const half8*)(bRow1 + o);
        acc0 = __builtin_amdgcn_mfma_f32_32x32x16_f16(af, b0, acc0, 0, 0, 0);
        acc1 = __builtin_amdgcn_mfma_f32_32x32x16_f16(af, b1, acc1, 0, 0, 0);
    }
    int rBase = rowBase + (wv & 1) * 32 + 4 * quad;
    #pragma unroll
    for (int r = 0; r < 16; r++){
        int outRow = rBase + (r & 3) + 8 * (r >> 2);
        if (outRow < N_NODES){
            outh[(size_t)outRow * D + c0] = __float2half(acc0[r]);
            outh[(size_t)outRow * D + c1] = __float2half(acc1[r]);
        }
    }
}

// ---------------- edge aggregation + bias + slot-scattered BN stats ------------
// NO fence / finalize here (R15 lesson). Finalize is fused into consumers.
__global__ __launch_bounds__(256) void k_agg(const __half* __restrict__ t,
                                             const int* __restrict__ row_ptr,
                                             const int* __restrict__ csr_src,
                                             const float* __restrict__ dinv,
                                             const float* __restrict__ selfw,
                                             const float* __restrict__ bias,
                                             float* __restrict__ outb,
                                             float* __restrict__ Spart,
                                             float* __restrict__ Qpart)
{
    __shared__ float ldsS[4][128];
    __shared__ float ldsQ[4][128];
    int lane = threadIdx.x & 63;
    int wv   = threadIdx.x >> 6;
    int i = blockIdx.x * 4 + wv;           // grid covers exactly N_NODES waves
    const __half2* t2 = (const __half2*)t;
    int p0 = row_ptr[i], p1 = row_ptr[i + 1];
    float sw = selfw[i];
    float dvi = dinv[i];
    float2 a = __half22float2(t2[(size_t)i * 64 + lane]);
    float ax = a.x * sw, ay = a.y * sw;
    int p = p0;
    for (; p + 8 <= p1; p += 8){
        int s[8]; float wv8[8];
        #pragma unroll
        for (int j = 0; j < 8; j++){ s[j] = csr_src[p + j]; }
        #pragma unroll
        for (int j = 0; j < 8; j++){ wv8[j] = dinv[s[j]] * dvi; }
        __half2 v[8];
        #pragma unroll
        for (int j = 0; j < 8; j++) v[j] = t2[(size_t)s[j] * 64 + lane];
        #pragma unroll
        for (int j = 0; j < 8; j++){
            float2 f = __half22float2(v[j]);
            ax = fmaf(wv8[j], f.x, ax);
            ay = fmaf(wv8[j], f.y, ay);
        }
    }
    for (; p + 4 <= p1; p += 4){
        int s0 = csr_src[p], s1 = csr_src[p+1], s2 = csr_src[p+2], s3 = csr_src[p+3];
        float w0 = dinv[s0] * dvi, w1 = dinv[s1] * dvi;
        float w2 = dinv[s2] * dvi, w3 = dinv[s3] * dvi;
        float2 v0 = __half22float2(t2[(size_t)s0 * 64 + lane]);
        float2 v1 = __half22float2(t2[(size_t)s1 * 64 + lane]);
        float2 v2 = __half22float2(t2[(size_t)s2 * 64 + lane]);
        float2 v3 = __half22float2(t2[(size_t)s3 * 64 + lane]);
        ax = fmaf(w0, v0.x, ax); ay = fmaf(w0, v0.y, ay);
        ax = fmaf(w1, v1.x, ax); ay = fmaf(w1, v1.y, ay);
        ax = fmaf(w2, v2.x, ax); ay = fmaf(w2, v2.y, ay);
        ax = fmaf(w3, v3.x, ax); ay = fmaf(w3, v3.y, ay);
    }
    for (; p < p1; ++p){
        int s = csr_src[p];
        float w = dinv[s] * dvi;
        float2 v = __half22float2(t2[(size_t)s * 64 + lane]);
        ax = fmaf(w, v.x, ax);
        ay = fmaf(w, v.y, ay);
    }
    float2 b2 = ((const float2*)bias)[lane];
    ax += b2.x; ay += b2.y;
    float2 o; o.x = ax; o.y = ay;
    ((float2*)outb)[(size_t)i * 64 + lane] = o;
    // stats epilogue: per-block reduce, slot-scattered atomics
    ldsS[wv][2 * lane] = ax;       ldsS[wv][2 * lane + 1] = ay;
    ldsQ[wv][2 * lane] = ax * ax;  ldsQ[wv][2 * lane + 1] = ay * ay;
    __syncthreads();
    int tid = threadIdx.x;
    int slotBase = (blockIdx.x & (NSLOT - 1)) * 128;
    if (tid < 128){
        float s = ldsS[0][tid] + ldsS[1][tid] + ldsS[2][tid] + ldsS[3][tid];
        atomicAdd(&Spart[slotBase + tid], s);
    } else {
        int f = tid - 128;
        float q = ldsQ[0][f] + ldsQ[1][f] + ldsQ[2][f] + ldsQ[3][f];
        atomicAdd(&Qpart[slotBase + f], q);
    }
}

// ---------------- pooled sum per graph + fused layer-2 BN finalize -------------
#define CHUNK 64
__global__ __launch_bounds__(256) void k_pool(const float* __restrict__ h,
                                              const int* __restrict__ batch,
                                              const float* __restrict__ Sp,
                                              const float* __restrict__ Qp,
                                              const float* __restrict__ gamma,
                                              const float* __restrict__ beta,
                                              float* __restrict__ pool)
{
    __shared__ float scsh[256];
    int tid = threadIdx.x;
    fin_to_lds(Sp, Qp, gamma, beta, scsh, tid);
    int lane = tid & 63;
    int wave = (blockIdx.x * blockDim.x + tid) >> 6;
    int i0 = wave * CHUNK;
    if (i0 >= N_NODES) return;
    int i1 = min(N_NODES, i0 + CHUNK);
    const float2* h2 = (const float2*)h;
    float2 scv = ((const float2*)scsh)[lane];
    float2 shv = ((const float2*)&scsh[128])[lane];
    int g = batch[i0];
    float ax = 0.f, ay = 0.f;
    for (int i = i0; i < i1; ++i){
        int gi = batch[i];
        if (gi != g){
            atomicAdd(&pool[g * 128 + 2 * lane],     ax);
            atomicAdd(&pool[g * 128 + 2 * lane + 1], ay);
            ax = 0.f; ay = 0.f; g = gi;
        }
        float2 v = h2[(size_t)i * 64 + lane];
        ax += relu_f(fmaf(v.x, scv.x, shv.x));
        ay += relu_f(fmaf(v.y, scv.y, shv.y));
    }
    atomicAdd(&pool[g * 128 + 2 * lane],     ax);
    atomicAdd(&pool[g * 128 + 2 * lane + 1], ay);
}

// ---------------- MLP head ----------------
__global__ __launch_bounds__(128) void k_head(const float* __restrict__ pool,
                                              const float* __restrict__ cnt,
                                              const float* __restrict__ W1,
                                              const float* __restrict__ b1,
                                              const float* __restrict__ W2,
                                              const float* __restrict__ b2,
                                              float* __restrict__ out)
{
    __shared__ float z[128];
    __shared__ float red[128];
    int g = blockIdx.x, f = threadIdx.x;
    float c = fmaxf(cnt[g], 1.0f);
    z[f] = pool[g * 128 + f] / c;
    __syncthreads();
    float a = b1[f];
    #pragma unroll 8
    for (int k = 0; k < 128; k++)
        a = fmaf(z[k], W1[k * 128 + f], a);
    a = relu_f(a);
    red[f] = a * W2[f];
    __syncthreads();
    for (int s2 = 64; s2 > 0; s2 >>= 1){
        if (f < s2) red[f] += red[f + s2];
        __syncthreads();
    }
    if (f == 0) out[g] = red[0] + b2[0];
}

extern "C" void kernel_launch(void* const* d_in, const int* in_sizes, int n_in,
                              void* d_out, int out_size, void* d_ws, size_t ws_size,
                              hipStream_t stream)
{
    const float* x      = (const float*)d_in[0];
    const int*   ei     = (const int*)d_in[1];
    const int*   batch  = (const int*)d_in[2];
    const float* Ws     = (const float*)d_in[3];
    const float* bs     = (const float*)d_in[4];
    const float* gammas = (const float*)d_in[5];
    const float* betas  = (const float*)d_in[6];
    const float* W1     = (const float*)d_in[7];
    const float* b1     = (const float*)d_in[8];
    const float* W2     = (const float*)d_in[9];
    const float* b2     = (const float*)d_in[10];
    float* out = (float*)d_out;

    const int* src = ei;
    const int* dst = ei + N_EDGES;

    char* w = (char*)d_ws;
    size_t off = 0;
    auto alloc = [&](size_t bytes) -> void* {
        void* p = w + off;
        off += (bytes + 255) & ~(size_t)255;
        return p;
    };
    int*   row_ptr     = (int*)  alloc((size_t)(N_NODES + 1) * 4);
    float* dinv        = (float*)alloc((size_t)N_NODES * 4);
    float* selfw       = (float*)alloc((size_t)N_NODES * 4);
    int*   csr_src     = (int*)  alloc((size_t)N_EDGES * 4);
    int*   blockHist   = (int*)  alloc((size_t)NBLK * NBUK * 4);
    int*   colScan     = (int*)  alloc((size_t)NBLK * NBUK * 4);
    int*   bucketTotal = (int*)  alloc((size_t)NBUK * 4);
    unsigned int* wpack = (unsigned int*)alloc((size_t)3 * 128 * 64 * 4);
    size_t zoff = off;                       // --- zero-span start ---
    float* stats       = (float*)alloc((size_t)3 * 2 * NSLOT * 128 * 4); // per layer: Spart, Qpart
    float* pool        = (float*)alloc((size_t)N_GRAPHS * 128 * 4);
    size_t zend = off;                       // --- zero-span end ---
    float* cnt         = (float*)alloc((size_t)N_GRAPHS * 4);
    __half* tbuf       = (__half*)alloc((size_t)N_NODES * 128 * 2);  // fp16 gather table
    float* hbuf        = (float*)alloc((size_t)N_NODES * 128 * 4);   // fp32 h
    if (off > ws_size) return;

    // alias scratch (consumed before tbuf is first written; stream-ordered)
    int2* ebuf = (int2*)tbuf;    // 6.4 MB < 25.6 MB

    k_front<<<NBLK + 96, 256, 0, stream>>>(dst, blockHist, Ws, wpack,
                                           (unsigned int*)(w + zoff),
                                           (int)((zend - zoff) >> 2),
                                           batch, cnt, row_ptr);
    k_p2a<<<NBUK, 256, 0, stream>>>(blockHist, colScan, bucketTotal);
    k_p3 <<<NBLK, 256, 0, stream>>>(src, dst, colScan, bucketTotal, ebuf);
    k_p4 <<<NBUK, 256, 0, stream>>>(ebuf, bucketTotal, row_ptr, csr_src, dinv, selfw);

    const float* curIn = x;
    for (int l = 0; l < 3; l++){
        float* Sp  = stats + (size_t)l * 2 * NSLOT * 128;
        float* Qp  = Sp + NSLOT * 128;
        float* SpP = stats + (size_t)(l - 1) * 2 * NSLOT * 128;  // prev layer
        float* QpP = SpP + NSLOT * 128;
        k_gemm<<<(N_NODES + 63) / 64, 256, 0, stream>>>(
            curIn, wpack + l * 8192,
            l ? SpP : nullptr, l ? QpP : nullptr,
            l ? gammas + (l - 1) * 128 : nullptr,
            l ? betas  + (l - 1) * 128 : nullptr,
            tbuf, l ? 1 : 0);
        k_agg<<<25000, 256, 0, stream>>>(
            tbuf, row_ptr, csr_src, dinv, selfw,
            bs + l * 128, hbuf, Sp, Qp);
        curIn = hbuf;
    }

    k_pool<<<391, 256, 0, stream>>>(hbuf, batch,
                                    stats + (size_t)2 * 2 * NSLOT * 128,
                                    stats + (size_t)2 * 2 * NSLOT * 128 + NSLOT * 128,
                                    gammas + 2 * 128, betas + 2 * 128, pool);
    k_head<<<512, 128, 0, stream>>>(pool, cnt, W1, b1, W2, b2, out);
}

// Round 18
// 420.721 us; speedup vs baseline: 1.2264x; 1.2264x over previous
//
#include <hip/hip_runtime.h>
#include <hip/hip_bf16.h>
#include <hip/hip_fp16.h>

#define N_NODES 100000
#define N_EDGES 800000
#define N_GRAPHS 512
#define D 128
#define EPSV 1e-5f

// radix-bucket CSR build params (256-node buckets)
#define NBLK 256
#define EPB  3125
#define NBUK 391          // ceil(100000/256)
#define MAXB 3072

// MFMA GEMM LDS layout (dwords): Ah 64 rows x 68dw, Wt2 128 cols x 68dw
#define LSTR 68
#define WOFF 4352

#define NSLOT 256         // stats scatter slots (queue depth 25000/256 ~ 98)

typedef _Float16 half8 __attribute__((ext_vector_type(8)));
typedef float floatx16 __attribute__((ext_vector_type(16)));

__device__ __forceinline__ float relu_f(float x){ return fmaxf(x, 0.0f); }

// inclusive scan of sd[0..511] with 256 threads
__device__ __forceinline__ void scan512(int* sd, int t)
{
    for (int off = 1; off < 512; off <<= 1){
        int i2 = t + 256;
        int v1 = (t  >= off) ? sd[t  - off] : 0;
        int v2 = (i2 >= off) ? sd[i2 - off] : 0;
        __syncthreads();
        sd[t]  += v1;
        sd[i2] += v2;
        __syncthreads();
    }
}

// ---------------- FRONT: p1 histogram (blocks 0..255) | wprep+zero+cnt (256..351)
__global__ __launch_bounds__(256) void k_front(const int* __restrict__ dst,
                                               int* __restrict__ blockHist,
                                               const float* __restrict__ Ws,
                                               unsigned int* __restrict__ wpack,
                                               unsigned int* __restrict__ zbase,
                                               int zn,
                                               const int* __restrict__ batch,
                                               float* __restrict__ cnt,
                                               int* __restrict__ row_ptr)
{
    __shared__ int h[NBUK];
    int j = blockIdx.x, t = threadIdx.x;
    if (j < NBLK){
        for (int u = t; u < NBUK; u += 256) h[u] = 0;
        __syncthreads();
        int e0 = j * EPB;
        for (int e = e0 + t; e < e0 + EPB; e += 256)
            atomicAdd(&h[dst[e] >> 8], 1);
        __syncthreads();
        for (int u = t; u < NBUK; u += 256) blockHist[j * NBUK + u] = h[u];
    } else {
        int b = j - NBLK;                 // 0..95
        int idx = b * 256 + t;
        if (idx == 0) row_ptr[N_NODES] = N_EDGES;
        if (idx < 3 * 128 * 64){
            int l  = idx >> 13;
            int r  = idx & 8191;
            int c  = r >> 6;
            int k2 = r & 63;
            const float* W = Ws + l * D * D;
            __half2 hh = __floats2half2_rn(W[(size_t)(2 * k2) * D + c],
                                           W[(size_t)(2 * k2 + 1) * D + c]);
            wpack[idx] = *(unsigned int*)&hh;
        }
        int stride = 96 * 256;
        for (int i = idx; i < zn; i += stride) zbase[i] = 0u;
        if (idx < N_GRAPHS){
            int g = idx;
            int lo = 0, hi = N_NODES;
            while (lo < hi){ int m = (lo + hi) >> 1; if (batch[m] < g) lo = m + 1; else hi = m; }
            int lb = lo;
            lo = 0; hi = N_NODES;
            while (lo < hi){ int m = (lo + hi) >> 1; if (batch[m] < g + 1) lo = m + 1; else hi = m; }
            cnt[g] = (float)(lo - lb);
        }
    }
}

// ---------------- P2a: per-bucket column scan (NBUK blocks, parallel) ----------
__global__ __launch_bounds__(256) void k_p2a(const int* __restrict__ blockHist,
                                             int* __restrict__ colScan,
                                             int* __restrict__ bucketTotal)
{
    __shared__ int sd[256];
    int b = blockIdx.x, t = threadIdx.x;
    int v = blockHist[t * NBUK + b];
    sd[t] = v;
    __syncthreads();
    for (int off = 1; off < 256; off <<= 1){
        int u = (t >= off) ? sd[t - off] : 0;
        __syncthreads();
        sd[t] += u;
        __syncthreads();
    }
    colScan[t * NBUK + b] = sd[t] - v;
    if (t == 255) bucketTotal[b] = sd[255];
}

// ---------------- P3: scatter edges into bucket-sorted ebuf (LDS cursors) ------
__global__ __launch_bounds__(256) void k_p3(const int* __restrict__ src,
                                            const int* __restrict__ dst,
                                            const int* __restrict__ colScan,
                                            const int* __restrict__ bucketTotal,
                                            int2* __restrict__ ebuf)
{
    __shared__ int sd[512];
    __shared__ int cur[NBUK];
    int j = blockIdx.x, t = threadIdx.x;
    int i2 = t + 256;
    sd[t]  = (t  < NBUK) ? bucketTotal[t]  : 0;
    sd[i2] = (i2 < NBUK) ? bucketTotal[i2] : 0;
    __syncthreads();
    scan512(sd, t);
    if (t < NBUK)
        cur[t]  = (sd[t]  - bucketTotal[t])  + colScan[j * NBUK + t];
    if (i2 < NBUK)
        cur[i2] = (sd[i2] - bucketTotal[i2]) + colScan[j * NBUK + i2];
    __syncthreads();
    int e0 = j * EPB;
    for (int e = e0 + t; e < e0 + EPB; e += 256){
        int s = src[e], d = dst[e];
        int pos = atomicAdd(&cur[d >> 8], 1);
        int2 v; v.x = s; v.y = d;
        ebuf[pos] = v;
    }
}

// ---------------- P4: per-bucket counting sort -> row_ptr, csr_src, dinv, selfw
__global__ __launch_bounds__(256) void k_p4(const int2* __restrict__ ebuf,
                                            const int* __restrict__ bucketTotal,
                                            int* __restrict__ row_ptr,
                                            int* __restrict__ csr_src,
                                            float* __restrict__ dinv,
                                            float* __restrict__ selfw)
{
    __shared__ int2 stash[MAXB];
    __shared__ int sdScan[512];
    __shared__ int bins[256];
    __shared__ int sd[256];
    int b = blockIdx.x, t = threadIdx.x;
    int i2 = t + 256;
    sdScan[t]  = (t  < NBUK) ? bucketTotal[t]  : 0;
    sdScan[i2] = (i2 < NBUK) ? bucketTotal[i2] : 0;
    __syncthreads();
    scan512(sdScan, t);
    int cntb = bucketTotal[b];
    int base = sdScan[b] - cntb;
    bool st = (cntb <= MAXB);
    bins[t] = 0;
    __syncthreads();
    for (int i = t; i < cntb; i += 256){
        int2 ed = ebuf[base + i];
        if (st) stash[i] = ed;
        atomicAdd(&bins[ed.y & 255], 1);
    }
    __syncthreads();
    int a0 = bins[t];
    sd[t] = a0;
    __syncthreads();
    for (int off = 1; off < 256; off <<= 1){
        int v = (t >= off) ? sd[t - off] : 0;
        __syncthreads();
        sd[t] += v;
        __syncthreads();
    }
    int pex = sd[t] - a0;
    int node = b * 256 + t;
    if (node < N_NODES){
        row_ptr[node] = base + pex;
        float d = (float)(a0 + 1);
        dinv[node]  = rsqrtf(d);
        selfw[node] = 1.0f / d;
    }
    __syncthreads();
    bins[t] = pex;
    __syncthreads();
    for (int i = t; i < cntb; i += 256){
        int2 ed = st ? stash[i] : ebuf[base + i];
        int pos = atomicAdd(&bins[ed.y & 255], 1);
        csr_src[base + pos] = ed.x;
    }
}

// ---------------- MFMA GEMM v2: A staged via LDS (coalesced), W prepacked ------
__global__ __launch_bounds__(256) void k_gemm(const float* __restrict__ A,
                                              const unsigned int* __restrict__ wp,
                                              const float* __restrict__ scale,
                                              const float* __restrict__ shift,
                                              __half* __restrict__ outh,
                                              int useBn)
{
    __shared__ unsigned int lds32[WOFF + 128 * LSTR];   // 52224 B
    int tid = threadIdx.x;
    int rowBase = blockIdx.x * 64;

    #pragma unroll
    for (int rep = 0; rep < 8; rep++){
        int f  = rep * 256 + tid;
        int m  = f >> 5;
        int c4 = f & 31;
        int row = rowBase + m;
        if (row >= N_NODES) row = N_NODES - 1;
        float4 v = *(const float4*)(A + (size_t)row * D + c4 * 4);
        if (useBn){
            float4 sc = *(const float4*)(scale + c4 * 4);
            float4 sh = *(const float4*)(shift + c4 * 4);
            v.x = relu_f(fmaf(v.x, sc.x, sh.x));
            v.y = relu_f(fmaf(v.y, sc.y, sh.y));
            v.z = relu_f(fmaf(v.z, sc.z, sh.z));
            v.w = relu_f(fmaf(v.w, sc.w, sh.w));
        }
        __half2 h0 = __floats2half2_rn(v.x, v.y);
        __half2 h1 = __floats2half2_rn(v.z, v.w);
        uint2 u; u.x = *(unsigned int*)&h0; u.y = *(unsigned int*)&h1;
        *(uint2*)&lds32[m * LSTR + 2 * c4] = u;
    }
    {
        const uint4* gw = (const uint4*)wp;
        #pragma unroll
        for (int rep = 0; rep < 8; rep++){
            int f = rep * 256 + tid;
            int c = f >> 4;
            int q = f & 15;
            uint4 v = gw[f];
            *(uint4*)&lds32[WOFF + c * LSTR + 4 * q] = v;
        }
    }
    __syncthreads();

    int lane = tid & 63, wv = tid >> 6;
    int quad = lane >> 5;
    int ml   = (lane & 31) + (wv & 1) * 32;
    int cA   = (wv >> 1) * 64;
    int c0   = cA + (lane & 31);
    int c1   = c0 + 32;
    const unsigned int* aRow  = lds32 + ml * LSTR;
    const unsigned int* bRow0 = lds32 + WOFF + c0 * LSTR;
    const unsigned int* bRow1 = lds32 + WOFF + c1 * LSTR;
    floatx16 acc0 = {};
    floatx16 acc1 = {};
    #pragma unroll
    for (int ch = 0; ch < 8; ch++){
        int o = ch * 8 + quad * 4;
        half8 af = *(const half8*)(aRow  + o);
        half8 b0 = *(const half8*)(bRow0 + o);
        half8 b1 = *(const half8*)(bRow1 + o);
        acc0 = __builtin_amdgcn_mfma_f32_32x32x16_f16(af, b0, acc0, 0, 0, 0);
        acc1 = __builtin_amdgcn_mfma_f32_32x32x16_f16(af, b1, acc1, 0, 0, 0);
    }
    int rBase = rowBase + (wv & 1) * 32 + 4 * quad;
    #pragma unroll
    for (int r = 0; r < 16; r++){
        int outRow = rBase + (r & 3) + 8 * (r >> 2);
        if (outRow < N_NODES){
            outh[(size_t)outRow * D + c0] = __float2half(acc0[r]);
            outh[(size_t)outRow * D + c1] = __float2half(acc1[r]);
        }
    }
}

// ---------------- edge aggregation + bias + slot-scattered BN stats ------------
// w on the fly: dinv[src]*dinv[i]. NO fence/finalize (R15: fence x 25K blocks
// = 2ms; R17: redundant per-block finalize = broadcast contention). Finalize
// stays a separate 1-block k_fin2.
__global__ __launch_bounds__(256) void k_agg(const __half* __restrict__ t,
                                             const int* __restrict__ row_ptr,
                                             const int* __restrict__ csr_src,
                                             const float* __restrict__ dinv,
                                             const float* __restrict__ selfw,
                                             const float* __restrict__ bias,
                                             float* __restrict__ outb,
                                             float* __restrict__ Spart,
                                             float* __restrict__ Qpart)
{
    __shared__ float ldsS[4][128];
    __shared__ float ldsQ[4][128];
    int lane = threadIdx.x & 63;
    int wv   = threadIdx.x >> 6;
    int i = blockIdx.x * 4 + wv;           // grid covers exactly N_NODES waves
    const __half2* t2 = (const __half2*)t;
    int p0 = row_ptr[i], p1 = row_ptr[i + 1];
    float sw = selfw[i];
    float dvi = dinv[i];
    float2 a = __half22float2(t2[(size_t)i * 64 + lane]);
    float ax = a.x * sw, ay = a.y * sw;
    int p = p0;
    for (; p + 8 <= p1; p += 8){
        int s[8]; float wv8[8];
        #pragma unroll
        for (int j = 0; j < 8; j++){ s[j] = csr_src[p + j]; }
        #pragma unroll
        for (int j = 0; j < 8; j++){ wv8[j] = dinv[s[j]] * dvi; }
        __half2 v[8];
        #pragma unroll
        for (int j = 0; j < 8; j++) v[j] = t2[(size_t)s[j] * 64 + lane];
        #pragma unroll
        for (int j = 0; j < 8; j++){
            float2 f = __half22float2(v[j]);
            ax = fmaf(wv8[j], f.x, ax);
            ay = fmaf(wv8[j], f.y, ay);
        }
    }
    for (; p + 4 <= p1; p += 4){
        int s0 = csr_src[p], s1 = csr_src[p+1], s2 = csr_src[p+2], s3 = csr_src[p+3];
        float w0 = dinv[s0] * dvi, w1 = dinv[s1] * dvi;
        float w2 = dinv[s2] * dvi, w3 = dinv[s3] * dvi;
        float2 v0 = __half22float2(t2[(size_t)s0 * 64 + lane]);
        float2 v1 = __half22float2(t2[(size_t)s1 * 64 + lane]);
        float2 v2 = __half22float2(t2[(size_t)s2 * 64 + lane]);
        float2 v3 = __half22float2(t2[(size_t)s3 * 64 + lane]);
        ax = fmaf(w0, v0.x, ax); ay = fmaf(w0, v0.y, ay);
        ax = fmaf(w1, v1.x, ax); ay = fmaf(w1, v1.y, ay);
        ax = fmaf(w2, v2.x, ax); ay = fmaf(w2, v2.y, ay);
        ax = fmaf(w3, v3.x, ax); ay = fmaf(w3, v3.y, ay);
    }
    for (; p < p1; ++p){
        int s = csr_src[p];
        float w = dinv[s] * dvi;
        float2 v = __half22float2(t2[(size_t)s * 64 + lane]);
        ax = fmaf(w, v.x, ax);
        ay = fmaf(w, v.y, ay);
    }
    float2 b2 = ((const float2*)bias)[lane];
    ax += b2.x; ay += b2.y;
    float2 o; o.x = ax; o.y = ay;
    ((float2*)outb)[(size_t)i * 64 + lane] = o;
    // stats epilogue: per-block reduce, slot-scattered atomics
    ldsS[wv][2 * lane] = ax;       ldsS[wv][2 * lane + 1] = ay;
    ldsQ[wv][2 * lane] = ax * ax;  ldsQ[wv][2 * lane + 1] = ay * ay;
    __syncthreads();
    int tid = threadIdx.x;
    int slotBase = (blockIdx.x & (NSLOT - 1)) * 128;
    if (tid < 128){
        float s = ldsS[0][tid] + ldsS[1][tid] + ldsS[2][tid] + ldsS[3][tid];
        atomicAdd(&Spart[slotBase + tid], s);
    } else {
        int f = tid - 128;
        float q = ldsQ[0][f] + ldsQ[1][f] + ldsQ[2][f] + ldsQ[3][f];
        atomicAdd(&Qpart[slotBase + f], q);
    }
}

// ---------------- finalize: reduce NSLOT slots -> scale/shift (1 block) --------
__global__ __launch_bounds__(256) void k_fin2(const float* __restrict__ Spart,
                                              const float* __restrict__ Qpart,
                                              const float* __restrict__ gamma,
                                              const float* __restrict__ beta,
                                              float* __restrict__ sc,
                                              float* __restrict__ sh)
{
    int t = threadIdx.x;
    int f = t & 127;
    const float* src = (t < 128) ? Spart : Qpart;
    float acc = 0.f;
    for (int s2 = 0; s2 < NSLOT; s2++)
        acc += src[s2 * 128 + f];
    __shared__ float red[256];
    red[t] = acc;
    __syncthreads();
    if (t < 128){
        float Sv = red[t];
        float Qv = red[t + 128];
        float mean = Sv * (1.0f / N_NODES);
        float var  = fmaxf(Qv * (1.0f / N_NODES) - mean * mean, 0.0f);
        float inv  = rsqrtf(var + EPSV);
        float gm = gamma[f] * inv;
        sc[f] = gm;
        sh[f] = beta[f] - mean * gm;
    }
}

// ---------------- pooled sum per graph (fp32 h) ----------------
#define CHUNK 64
__global__ __launch_bounds__(256) void k_pool(const float* __restrict__ h,
                                              const int* __restrict__ batch,
                                              const float* __restrict__ sc,
                                              const float* __restrict__ sh,
                                              float* __restrict__ pool)
{
    int lane = threadIdx.x & 63;
    int wave = (blockIdx.x * blockDim.x + threadIdx.x) >> 6;
    int i0 = wave * CHUNK;
    if (i0 >= N_NODES) return;
    int i1 = min(N_NODES, i0 + CHUNK);
    const float2* h2 = (const float2*)h;
    float2 scv = ((const float2*)sc)[lane];
    float2 shv = ((const float2*)sh)[lane];
    int g = batch[i0];
    float ax = 0.f, ay = 0.f;
    for (int i = i0; i < i1; ++i){
        int gi = batch[i];
        if (gi != g){
            atomicAdd(&pool[g * 128 + 2 * lane],     ax);
            atomicAdd(&pool[g * 128 + 2 * lane + 1], ay);
            ax = 0.f; ay = 0.f; g = gi;
        }
        float2 v = h2[(size_t)i * 64 + lane];
        ax += relu_f(fmaf(v.x, scv.x, shv.x));
        ay += relu_f(fmaf(v.y, scv.y, shv.y));
    }
    atomicAdd(&pool[g * 128 + 2 * lane],     ax);
    atomicAdd(&pool[g * 128 + 2 * lane + 1], ay);
}

// ---------------- MLP head ----------------
__global__ __launch_bounds__(128) void k_head(const float* __restrict__ pool,
                                              const float* __restrict__ cnt,
                                              const float* __restrict__ W1,
                                              const float* __restrict__ b1,
                                              const float* __restrict__ W2,
                                              const float* __restrict__ b2,
                                              float* __restrict__ out)
{
    __shared__ float z[128];
    __shared__ float red[128];
    int g = blockIdx.x, f = threadIdx.x;
    float c = fmaxf(cnt[g], 1.0f);
    z[f] = pool[g * 128 + f] / c;
    __syncthreads();
    float a = b1[f];
    #pragma unroll 8
    for (int k = 0; k < 128; k++)
        a = fmaf(z[k], W1[k * 128 + f], a);
    a = relu_f(a);
    red[f] = a * W2[f];
    __syncthreads();
    for (int s2 = 64; s2 > 0; s2 >>= 1){
        if (f < s2) red[f] += red[f + s2];
        __syncthreads();
    }
    if (f == 0) out[g] = red[0] + b2[0];
}

extern "C" void kernel_launch(void* const* d_in, const int* in_sizes, int n_in,
                              void* d_out, int out_size, void* d_ws, size_t ws_size,
                              hipStream_t stream)
{
    const float* x      = (const float*)d_in[0];
    const int*   ei     = (const int*)d_in[1];
    const int*   batch  = (const int*)d_in[2];
    const float* Ws     = (const float*)d_in[3];
    const float* bs     = (const float*)d_in[4];
    const float* gammas = (const float*)d_in[5];
    const float* betas  = (const float*)d_in[6];
    const float* W1     = (const float*)d_in[7];
    const float* b1     = (const float*)d_in[8];
    const float* W2     = (const float*)d_in[9];
    const float* b2     = (const float*)d_in[10];
    float* out = (float*)d_out;

    const int* src = ei;
    const int* dst = ei + N_EDGES;

    char* w = (char*)d_ws;
    size_t off = 0;
    auto alloc = [&](size_t bytes) -> void* {
        void* p = w + off;
        off += (bytes + 255) & ~(size_t)255;
        return p;
    };
    int*   row_ptr     = (int*)  alloc((size_t)(N_NODES + 1) * 4);
    float* dinv        = (float*)alloc((size_t)N_NODES * 4);
    float* selfw       = (float*)alloc((size_t)N_NODES * 4);
    int*   csr_src     = (int*)  alloc((size_t)N_EDGES * 4);
    int*   blockHist   = (int*)  alloc((size_t)NBLK * NBUK * 4);
    int*   colScan     = (int*)  alloc((size_t)NBLK * NBUK * 4);
    int*   bucketTotal = (int*)  alloc((size_t)NBUK * 4);
    unsigned int* wpack = (unsigned int*)alloc((size_t)3 * 128 * 64 * 4);
    size_t zoff = off;                       // --- zero-span start ---
    float* stats       = (float*)alloc((size_t)3 * 2 * NSLOT * 128 * 4); // per layer: Spart, Qpart
    float* pool        = (float*)alloc((size_t)N_GRAPHS * 128 * 4);
    size_t zend = off;                       // --- zero-span end ---
    float* cnt         = (float*)alloc((size_t)N_GRAPHS * 4);
    float* ssh         = (float*)alloc(3 * 256 * 4);   // per layer: scale, shift
    __half* tbuf       = (__half*)alloc((size_t)N_NODES * 128 * 2);  // fp16 gather table
    float* hbuf        = (float*)alloc((size_t)N_NODES * 128 * 4);   // fp32 h
    if (off > ws_size) return;

    // alias scratch (consumed before tbuf is first written; stream-ordered)
    int2* ebuf = (int2*)tbuf;    // 6.4 MB < 25.6 MB

    k_front<<<NBLK + 96, 256, 0, stream>>>(dst, blockHist, Ws, wpack,
                                           (unsigned int*)(w + zoff),
                                           (int)((zend - zoff) >> 2),
                                           batch, cnt, row_ptr);
    k_p2a<<<NBUK, 256, 0, stream>>>(blockHist, colScan, bucketTotal);
    k_p3 <<<NBLK, 256, 0, stream>>>(src, dst, colScan, bucketTotal, ebuf);
    k_p4 <<<NBUK, 256, 0, stream>>>(ebuf, bucketTotal, row_ptr, csr_src, dinv, selfw);

    const float* curIn = x;
    for (int l = 0; l < 3; l++){
        float* Sp = stats + (size_t)l * 2 * NSLOT * 128;
        float* Qp = Sp + NSLOT * 128;
        k_gemm<<<(N_NODES + 63) / 64, 256, 0, stream>>>(
            curIn, wpack + l * 8192,
            l ? ssh + (l - 1) * 256       : nullptr,
            l ? ssh + (l - 1) * 256 + 128 : nullptr,
            tbuf, l ? 1 : 0);
        k_agg<<<25000, 256, 0, stream>>>(
            tbuf, row_ptr, csr_src, dinv, selfw,
            bs + l * 128, hbuf, Sp, Qp);
        k_fin2<<<1, 256, 0, stream>>>(
            Sp, Qp, gammas + l * 128, betas + l * 128,
            ssh + l * 256, ssh + l * 256 + 128);
        curIn = hbuf;
    }

    k_pool<<<391, 256, 0, stream>>>(hbuf, batch, ssh + 2 * 256, ssh + 2 * 256 + 128, pool);
    k_head<<<512, 128, 0, stream>>>(pool, cnt, W1, b1, W2, b2, out);
}

// Round 19
// 412.091 us; speedup vs baseline: 1.2520x; 1.0209x over previous
//
#include <hip/hip_runtime.h>
#include <hip/hip_bf16.h>
#include <hip/hip_fp16.h>

#define N_NODES 100000
#define N_EDGES 800000
#define N_GRAPHS 512
#define D 128
#define EPSV 1e-5f

// radix-bucket CSR build params (256-node buckets)
#define NBLK 256
#define EPB  3125
#define NBUK 391          // ceil(100000/256)
#define MAXB 3072

// MFMA GEMM LDS layout (dwords): Ah 64 rows x 68dw, Wt2 128 cols x 68dw
#define LSTR 68
#define WOFF 4352

#define NSLOT 256         // stats scatter slots (queue depth 25000/256 ~ 98)

typedef _Float16 half8 __attribute__((ext_vector_type(8)));
typedef float floatx16 __attribute__((ext_vector_type(16)));

__device__ __forceinline__ float relu_f(float x){ return fmaxf(x, 0.0f); }

// inclusive scan of sd[0..511] with 256 threads
__device__ __forceinline__ void scan512(int* sd, int t)
{
    for (int off = 1; off < 512; off <<= 1){
        int i2 = t + 256;
        int v1 = (t  >= off) ? sd[t  - off] : 0;
        int v2 = (i2 >= off) ? sd[i2 - off] : 0;
        __syncthreads();
        sd[t]  += v1;
        sd[i2] += v2;
        __syncthreads();
    }
}

// ---------------- FRONT: p1 histogram (blocks 0..255) | wprep+zero+gstart ------
__global__ __launch_bounds__(256) void k_front(const int* __restrict__ dst,
                                               int* __restrict__ blockHist,
                                               const float* __restrict__ Ws,
                                               unsigned int* __restrict__ wpack,
                                               unsigned int* __restrict__ zbase,
                                               int zn,
                                               const int* __restrict__ batch,
                                               int* __restrict__ gstart,
                                               int* __restrict__ row_ptr)
{
    __shared__ int h[NBUK];
    int j = blockIdx.x, t = threadIdx.x;
    if (j < NBLK){
        for (int u = t; u < NBUK; u += 256) h[u] = 0;
        __syncthreads();
        int e0 = j * EPB;
        for (int e = e0 + t; e < e0 + EPB; e += 256)
            atomicAdd(&h[dst[e] >> 8], 1);
        __syncthreads();
        for (int u = t; u < NBUK; u += 256) blockHist[j * NBUK + u] = h[u];
    } else {
        int b = j - NBLK;                 // 0..95
        int idx = b * 256 + t;
        if (idx == 0){
            row_ptr[N_NODES] = N_EDGES;
            gstart[N_GRAPHS] = N_NODES;
        }
        if (idx < 3 * 128 * 64){
            int l  = idx >> 13;
            int r  = idx & 8191;
            int c  = r >> 6;
            int k2 = r & 63;
            const float* W = Ws + l * D * D;
            __half2 hh = __floats2half2_rn(W[(size_t)(2 * k2) * D + c],
                                           W[(size_t)(2 * k2 + 1) * D + c]);
            wpack[idx] = *(unsigned int*)&hh;
        }
        int stride = 96 * 256;
        for (int i = idx; i < zn; i += stride) zbase[i] = 0u;
        if (idx < N_GRAPHS){
            int g = idx;
            int lo = 0, hi = N_NODES;
            while (lo < hi){ int m = (lo + hi) >> 1; if (batch[m] < g) lo = m + 1; else hi = m; }
            gstart[g] = lo;
        }
    }
}

// ---------------- P2a: per-bucket column scan (NBUK blocks, parallel) ----------
__global__ __launch_bounds__(256) void k_p2a(const int* __restrict__ blockHist,
                                             int* __restrict__ colScan,
                                             int* __restrict__ bucketTotal)
{
    __shared__ int sd[256];
    int b = blockIdx.x, t = threadIdx.x;
    int v = blockHist[t * NBUK + b];
    sd[t] = v;
    __syncthreads();
    for (int off = 1; off < 256; off <<= 1){
        int u = (t >= off) ? sd[t - off] : 0;
        __syncthreads();
        sd[t] += u;
        __syncthreads();
    }
    colScan[t * NBUK + b] = sd[t] - v;
    if (t == 255) bucketTotal[b] = sd[255];
}

// ---------------- P3: scatter edges into bucket-sorted ebuf (LDS cursors) ------
__global__ __launch_bounds__(256) void k_p3(const int* __restrict__ src,
                                            const int* __restrict__ dst,
                                            const int* __restrict__ colScan,
                                            const int* __restrict__ bucketTotal,
                                            int2* __restrict__ ebuf)
{
    __shared__ int sd[512];
    __shared__ int cur[NBUK];
    int j = blockIdx.x, t = threadIdx.x;
    int i2 = t + 256;
    sd[t]  = (t  < NBUK) ? bucketTotal[t]  : 0;
    sd[i2] = (i2 < NBUK) ? bucketTotal[i2] : 0;
    __syncthreads();
    scan512(sd, t);
    if (t < NBUK)
        cur[t]  = (sd[t]  - bucketTotal[t])  + colScan[j * NBUK + t];
    if (i2 < NBUK)
        cur[i2] = (sd[i2] - bucketTotal[i2]) + colScan[j * NBUK + i2];
    __syncthreads();
    int e0 = j * EPB;
    for (int e = e0 + t; e < e0 + EPB; e += 256){
        int s = src[e], d = dst[e];
        int pos = atomicAdd(&cur[d >> 8], 1);
        int2 v; v.x = s; v.y = d;
        ebuf[pos] = v;
    }
}

// ---------------- P4: per-bucket counting sort -> row_ptr, csr_src, dinv, selfw
__global__ __launch_bounds__(256) void k_p4(const int2* __restrict__ ebuf,
                                            const int* __restrict__ bucketTotal,
                                            int* __restrict__ row_ptr,
                                            int* __restrict__ csr_src,
                                            float* __restrict__ dinv,
                                            float* __restrict__ selfw)
{
    __shared__ int2 stash[MAXB];
    __shared__ int sdScan[512];
    __shared__ int bins[256];
    __shared__ int sd[256];
    int b = blockIdx.x, t = threadIdx.x;
    int i2 = t + 256;
    sdScan[t]  = (t  < NBUK) ? bucketTotal[t]  : 0;
    sdScan[i2] = (i2 < NBUK) ? bucketTotal[i2] : 0;
    __syncthreads();
    scan512(sdScan, t);
    int cntb = bucketTotal[b];
    int base = sdScan[b] - cntb;
    bool st = (cntb <= MAXB);
    bins[t] = 0;
    __syncthreads();
    for (int i = t; i < cntb; i += 256){
        int2 ed = ebuf[base + i];
        if (st) stash[i] = ed;
        atomicAdd(&bins[ed.y & 255], 1);
    }
    __syncthreads();
    int a0 = bins[t];
    sd[t] = a0;
    __syncthreads();
    for (int off = 1; off < 256; off <<= 1){
        int v = (t >= off) ? sd[t - off] : 0;
        __syncthreads();
        sd[t] += v;
        __syncthreads();
    }
    int pex = sd[t] - a0;
    int node = b * 256 + t;
    if (node < N_NODES){
        row_ptr[node] = base + pex;
        float d = (float)(a0 + 1);
        dinv[node]  = rsqrtf(d);
        selfw[node] = 1.0f / d;
    }
    __syncthreads();
    bins[t] = pex;
    __syncthreads();
    for (int i = t; i < cntb; i += 256){
        int2 ed = st ? stash[i] : ebuf[base + i];
        int pos = atomicAdd(&bins[ed.y & 255], 1);
        csr_src[base + pos] = ed.x;
    }
}

// ---------------- MFMA GEMM v2: A staged via LDS (coalesced), W prepacked ------
__global__ __launch_bounds__(256) void k_gemm(const float* __restrict__ A,
                                              const unsigned int* __restrict__ wp,
                                              const float* __restrict__ scale,
                                              const float* __restrict__ shift,
                                              __half* __restrict__ outh,
                                              int useBn)
{
    __shared__ unsigned int lds32[WOFF + 128 * LSTR];   // 52224 B
    int tid = threadIdx.x;
    int rowBase = blockIdx.x * 64;

    #pragma unroll
    for (int rep = 0; rep < 8; rep++){
        int f  = rep * 256 + tid;
        int m  = f >> 5;
        int c4 = f & 31;
        int row = rowBase + m;
        if (row >= N_NODES) row = N_NODES - 1;
        float4 v = *(const float4*)(A + (size_t)row * D + c4 * 4);
        if (useBn){
            float4 sc = *(const float4*)(scale + c4 * 4);
            float4 sh = *(const float4*)(shift + c4 * 4);
            v.x = relu_f(fmaf(v.x, sc.x, sh.x));
            v.y = relu_f(fmaf(v.y, sc.y, sh.y));
            v.z = relu_f(fmaf(v.z, sc.z, sh.z));
            v.w = relu_f(fmaf(v.w, sc.w, sh.w));
        }
        __half2 h0 = __floats2half2_rn(v.x, v.y);
        __half2 h1 = __floats2half2_rn(v.z, v.w);
        uint2 u; u.x = *(unsigned int*)&h0; u.y = *(unsigned int*)&h1;
        *(uint2*)&lds32[m * LSTR + 2 * c4] = u;
    }
    {
        const uint4* gw = (const uint4*)wp;
        #pragma unroll
        for (int rep = 0; rep < 8; rep++){
            int f = rep * 256 + tid;
            int c = f >> 4;
            int q = f & 15;
            uint4 v = gw[f];
            *(uint4*)&lds32[WOFF + c * LSTR + 4 * q] = v;
        }
    }
    __syncthreads();

    int lane = tid & 63, wv = tid >> 6;
    int quad = lane >> 5;
    int ml   = (lane & 31) + (wv & 1) * 32;
    int cA   = (wv >> 1) * 64;
    int c0   = cA + (lane & 31);
    int c1   = c0 + 32;
    const unsigned int* aRow  = lds32 + ml * LSTR;
    const unsigned int* bRow0 = lds32 + WOFF + c0 * LSTR;
    const unsigned int* bRow1 = lds32 + WOFF + c1 * LSTR;
    floatx16 acc0 = {};
    floatx16 acc1 = {};
    #pragma unroll
    for (int ch = 0; ch < 8; ch++){
        int o = ch * 8 + quad * 4;
        half8 af = *(const half8*)(aRow  + o);
        half8 b0 = *(const half8*)(bRow0 + o);
        half8 b1 = *(const half8*)(bRow1 + o);
        acc0 = __builtin_amdgcn_mfma_f32_32x32x16_f16(af, b0, acc0, 0, 0, 0);
        acc1 = __builtin_amdgcn_mfma_f32_32x32x16_f16(af, b1, acc1, 0, 0, 0);
    }
    int rBase = rowBase + (wv & 1) * 32 + 4 * quad;
    #pragma unroll
    for (int r = 0; r < 16; r++){
        int outRow = rBase + (r & 3) + 8 * (r >> 2);
        if (outRow < N_NODES){
            outh[(size_t)outRow * D + c0] = __float2half(acc0[r]);
            outh[(size_t)outRow * D + c1] = __float2half(acc1[r]);
        }
    }
}

// ---------------- edge aggregation + bias + slot-scattered BN stats ------------
// w on the fly: dinv[src]*dinv[i]. NO fence/finalize (R15/R17 lessons).
__global__ __launch_bounds__(256) void k_agg(const __half* __restrict__ t,
                                             const int* __restrict__ row_ptr,
                                             const int* __restrict__ csr_src,
                                             const float* __restrict__ dinv,
                                             const float* __restrict__ selfw,
                                             const float* __restrict__ bias,
                                             float* __restrict__ outb,
                                             float* __restrict__ Spart,
                                             float* __restrict__ Qpart)
{
    __shared__ float ldsS[4][128];
    __shared__ float ldsQ[4][128];
    int lane = threadIdx.x & 63;
    int wv   = threadIdx.x >> 6;
    int i = blockIdx.x * 4 + wv;           // grid covers exactly N_NODES waves
    const __half2* t2 = (const __half2*)t;
    int p0 = row_ptr[i], p1 = row_ptr[i + 1];
    float sw = selfw[i];
    float dvi = dinv[i];
    float2 a = __half22float2(t2[(size_t)i * 64 + lane]);
    float ax = a.x * sw, ay = a.y * sw;
    int p = p0;
    for (; p + 8 <= p1; p += 8){
        int s[8]; float wv8[8];
        #pragma unroll
        for (int j = 0; j < 8; j++){ s[j] = csr_src[p + j]; }
        #pragma unroll
        for (int j = 0; j < 8; j++){ wv8[j] = dinv[s[j]] * dvi; }
        __half2 v[8];
        #pragma unroll
        for (int j = 0; j < 8; j++) v[j] = t2[(size_t)s[j] * 64 + lane];
        #pragma unroll
        for (int j = 0; j < 8; j++){
            float2 f = __half22float2(v[j]);
            ax = fmaf(wv8[j], f.x, ax);
            ay = fmaf(wv8[j], f.y, ay);
        }
    }
    for (; p + 4 <= p1; p += 4){
        int s0 = csr_src[p], s1 = csr_src[p+1], s2 = csr_src[p+2], s3 = csr_src[p+3];
        float w0 = dinv[s0] * dvi, w1 = dinv[s1] * dvi;
        float w2 = dinv[s2] * dvi, w3 = dinv[s3] * dvi;
        float2 v0 = __half22float2(t2[(size_t)s0 * 64 + lane]);
        float2 v1 = __half22float2(t2[(size_t)s1 * 64 + lane]);
        float2 v2 = __half22float2(t2[(size_t)s2 * 64 + lane]);
        float2 v3 = __half22float2(t2[(size_t)s3 * 64 + lane]);
        ax = fmaf(w0, v0.x, ax); ay = fmaf(w0, v0.y, ay);
        ax = fmaf(w1, v1.x, ax); ay = fmaf(w1, v1.y, ay);
        ax = fmaf(w2, v2.x, ax); ay = fmaf(w2, v2.y, ay);
        ax = fmaf(w3, v3.x, ax); ay = fmaf(w3, v3.y, ay);
    }
    for (; p < p1; ++p){
        int s = csr_src[p];
        float w = dinv[s] * dvi;
        float2 v = __half22float2(t2[(size_t)s * 64 + lane]);
        ax = fmaf(w, v.x, ax);
        ay = fmaf(w, v.y, ay);
    }
    float2 b2 = ((const float2*)bias)[lane];
    ax += b2.x; ay += b2.y;
    float2 o; o.x = ax; o.y = ay;
    ((float2*)outb)[(size_t)i * 64 + lane] = o;
    // stats epilogue: per-block reduce, slot-scattered atomics
    ldsS[wv][2 * lane] = ax;       ldsS[wv][2 * lane + 1] = ay;
    ldsQ[wv][2 * lane] = ax * ax;  ldsQ[wv][2 * lane + 1] = ay * ay;
    __syncthreads();
    int tid = threadIdx.x;
    int slotBase = (blockIdx.x & (NSLOT - 1)) * 128;
    if (tid < 128){
        float s = ldsS[0][tid] + ldsS[1][tid] + ldsS[2][tid] + ldsS[3][tid];
        atomicAdd(&Spart[slotBase + tid], s);
    } else {
        int f = tid - 128;
        float q = ldsQ[0][f] + ldsQ[1][f] + ldsQ[2][f] + ldsQ[3][f];
        atomicAdd(&Qpart[slotBase + f], q);
    }
}

// ---------------- finalize: reduce NSLOT slots -> scale/shift (1 block) --------
__global__ __launch_bounds__(256) void k_fin2(const float* __restrict__ Spart,
                                              const float* __restrict__ Qpart,
                                              const float* __restrict__ gamma,
                                              const float* __restrict__ beta,
                                              float* __restrict__ sc,
                                              float* __restrict__ sh)
{
    int t = threadIdx.x;
    int f = t & 127;
    const float* src = (t < 128) ? Spart : Qpart;
    float acc = 0.f;
    for (int s2 = 0; s2 < NSLOT; s2++)
        acc += src[s2 * 128 + f];
    __shared__ float red[256];
    red[t] = acc;
    __syncthreads();
    if (t < 128){
        float Sv = red[t];
        float Qv = red[t + 128];
        float mean = Sv * (1.0f / N_NODES);
        float var  = fmaxf(Qv * (1.0f / N_NODES) - mean * mean, 0.0f);
        float inv  = rsqrtf(var + EPSV);
        float gm = gamma[f] * inv;
        sc[f] = gm;
        sh[f] = beta[f] - mean * gm;
    }
}

// ---------------- TAIL: per-graph BN+ReLU+mean + MLP head (one block/graph) ----
__global__ __launch_bounds__(256) void k_tail(const float* __restrict__ h,
                                              const int* __restrict__ gstart,
                                              const float* __restrict__ sc,
                                              const float* __restrict__ sh,
                                              const float* __restrict__ W1,
                                              const float* __restrict__ b1,
                                              const float* __restrict__ W2,
                                              const float* __restrict__ b2,
                                              float* __restrict__ out)
{
    __shared__ float part[256];
    __shared__ float z[128];
    __shared__ float red[128];
    int g = blockIdx.x;
    int tid = threadIdx.x;
    int f = tid & 127;
    int hf = tid >> 7;                // 0/1: row-parity split
    int s0 = gstart[g], s1 = gstart[g + 1];
    float scv = sc[f], shv = sh[f];
    float acc = 0.f;
    for (int i = s0 + hf; i < s1; i += 2)
        acc += relu_f(fmaf(h[(size_t)i * D + f], scv, shv));
    part[tid] = acc;
    __syncthreads();
    if (tid < 128){
        float c = fmaxf((float)(s1 - s0), 1.0f);
        z[f] = (part[f] + part[f + 128]) / c;
    }
    __syncthreads();
    // head GEMV: thread (f,hf) covers k in [hf*64, hf*64+64)
    float a = 0.f;
    int k0 = hf * 64;
    #pragma unroll 8
    for (int k = k0; k < k0 + 64; k++)
        a = fmaf(z[k], W1[k * D + f], a);
    part[tid] = a;
    __syncthreads();
    if (tid < 128){
        float av = relu_f(part[f] + part[f + 128] + b1[f]);
        red[f] = av * W2[f];
    }
    __syncthreads();
    for (int s2 = 64; s2 > 0; s2 >>= 1){
        if (tid < s2) red[tid] += red[tid + s2];
        __syncthreads();
    }
    if (tid == 0) out[g] = red[0] + b2[0];
}

extern "C" void kernel_launch(void* const* d_in, const int* in_sizes, int n_in,
                              void* d_out, int out_size, void* d_ws, size_t ws_size,
                              hipStream_t stream)
{
    const float* x      = (const float*)d_in[0];
    const int*   ei     = (const int*)d_in[1];
    const int*   batch  = (const int*)d_in[2];
    const float* Ws     = (const float*)d_in[3];
    const float* bs     = (const float*)d_in[4];
    const float* gammas = (const float*)d_in[5];
    const float* betas  = (const float*)d_in[6];
    const float* W1     = (const float*)d_in[7];
    const float* b1     = (const float*)d_in[8];
    const float* W2     = (const float*)d_in[9];
    const float* b2     = (const float*)d_in[10];
    float* out = (float*)d_out;

    const int* src = ei;
    const int* dst = ei + N_EDGES;

    char* w = (char*)d_ws;
    size_t off = 0;
    auto alloc = [&](size_t bytes) -> void* {
        void* p = w + off;
        off += (bytes + 255) & ~(size_t)255;
        return p;
    };
    int*   row_ptr     = (int*)  alloc((size_t)(N_NODES + 1) * 4);
    float* dinv        = (float*)alloc((size_t)N_NODES * 4);
    float* selfw       = (float*)alloc((size_t)N_NODES * 4);
    int*   csr_src     = (int*)  alloc((size_t)N_EDGES * 4);
    int*   blockHist   = (int*)  alloc((size_t)NBLK * NBUK * 4);
    int*   colScan     = (int*)  alloc((size_t)NBLK * NBUK * 4);
    int*   bucketTotal = (int*)  alloc((size_t)NBUK * 4);
    unsigned int* wpack = (unsigned int*)alloc((size_t)3 * 128 * 64 * 4);
    int*   gstart      = (int*)  alloc((size_t)(N_GRAPHS + 1) * 4);
    size_t zoff = off;                       // --- zero-span start ---
    float* stats       = (float*)alloc((size_t)3 * 2 * NSLOT * 128 * 4); // per layer: Spart, Qpart
    size_t zend = off;                       // --- zero-span end ---
    float* ssh         = (float*)alloc(3 * 256 * 4);   // per layer: scale, shift
    __half* tbuf       = (__half*)alloc((size_t)N_NODES * 128 * 2);  // fp16 gather table
    float* hbuf        = (float*)alloc((size_t)N_NODES * 128 * 4);   // fp32 h
    if (off > ws_size) return;

    // alias scratch (consumed before tbuf is first written; stream-ordered)
    int2* ebuf = (int2*)tbuf;    // 6.4 MB < 25.6 MB

    k_front<<<NBLK + 96, 256, 0, stream>>>(dst, blockHist, Ws, wpack,
                                           (unsigned int*)(w + zoff),
                                           (int)((zend - zoff) >> 2),
                                           batch, gstart, row_ptr);
    k_p2a<<<NBUK, 256, 0, stream>>>(blockHist, colScan, bucketTotal);
    k_p3 <<<NBLK, 256, 0, stream>>>(src, dst, colScan, bucketTotal, ebuf);
    k_p4 <<<NBUK, 256, 0, stream>>>(ebuf, bucketTotal, row_ptr, csr_src, dinv, selfw);

    const float* curIn = x;
    for (int l = 0; l < 3; l++){
        float* Sp = stats + (size_t)l * 2 * NSLOT * 128;
        float* Qp = Sp + NSLOT * 128;
        k_gemm<<<(N_NODES + 63) / 64, 256, 0, stream>>>(
            curIn, wpack + l * 8192,
            l ? ssh + (l - 1) * 256       : nullptr,
            l ? ssh + (l - 1) * 256 + 128 : nullptr,
            tbuf, l ? 1 : 0);
        k_agg<<<25000, 256, 0, stream>>>(
            tbuf, row_ptr, csr_src, dinv, selfw,
            bs + l * 128, hbuf, Sp, Qp);
        k_fin2<<<1, 256, 0, stream>>>(
            Sp, Qp, gammas + l * 128, betas + l * 128,
            ssh + l * 256, ssh + l * 256 + 128);
        curIn = hbuf;
    }

    k_tail<<<N_GRAPHS, 256, 0, stream>>>(hbuf, gstart,
                                         ssh + 2 * 256, ssh + 2 * 256 + 128,
                                         W1, b1, W2, b2, out);
}